// Round 5
// baseline (959.679 us; speedup 1.0000x reference)
//
#include <hip/hip_runtime.h>
#include <stdint.h>

// ManualLSTM: B=512, T=1024, D=64, U=128.
// R12: latency-hiding via 2 independent chains per CU.
//  - ROWS=1, NBLK=512, 2 blocks/CU (launch_bounds(512,2); LDS 2x68KB fits
//    160KB; VGPR 128 -> 4 waves/SIMD). The 16x16x128 MFMA tile count per
//    block is independent of ROWS (M-dim was 8x-wasted), so per-block work
//    is unchanged; two co-resident blocks interleave their barrier/ds-latency
//    /activation phases against each other's MFMA bursts.
//  - Row duplication keeps the code shape: both prow halves compute the same
//    batch row (producer Gx rows 2j/2j+1 identical); only prow==0 writes out.
//  - Consumer order = R8's verified burst-then-activate (R11's gate-major
//    interleave cost ~160 cyc/step in mid-burst result waits; reverted).
//  - Math = R9's verified log2e fold (producer stores scg*(xW+b), consumer
//    gate arg = 1 FMA into fsig2/fth2).
// Structure: waves 0-3 consumers (h.U scaled fp8 MFMA chain, prio1),
// waves 4-7 producers (x.W bf16 MFMA, 1 tile/step).
// Gx race-free: consumers read Gx[g&1], producers write Gx[(g+1)&1].
// A1 (h fp8) step-parity dbuf; sync_lds drains lgkm only (x loads in flight).

typedef __attribute__((ext_vector_type(8))) short short8;
typedef __attribute__((ext_vector_type(4))) float floatx4;
typedef __attribute__((ext_vector_type(4))) int   intx4;
typedef __attribute__((ext_vector_type(8))) int   intx8;

#define B_SZ   512
#define T_SZ   1024
#define D_SZ   64
#define U_SZ   128
#define ROWS   1
#define NBLK   (B_SZ / ROWS)   // 512 blocks -> 2 blocks/CU
#define NTHR   512             // 8 waves: 0-3 consumers, 4-7 producers
#define A1STRB 160             // h row stride in BYTES (128 fp8 + 32 pad)
#define GXSTR  524             // Gx row stride in fp32
#define L2E    1.4426950408889634f

__device__ __forceinline__ short f2bf(float f) {
    uint32_t u = __builtin_bit_cast(uint32_t, f);
    uint32_t r = (u + 0x7fffu + ((u >> 16) & 1u)) >> 16;   // RNE
    return (short)r;
}
__device__ __forceinline__ int cvt2bf(float lo, float hi) {
    int r;
    asm("v_cvt_pk_bf16_f32 %0, %1, %2" : "=v"(r) : "v"(lo), "v"(hi));
    return r;
}
__device__ __forceinline__ short8 pk8(float4 a, float4 b) {
    intx4 t = {cvt2bf(a.x, a.y), cvt2bf(a.z, a.w), cvt2bf(b.x, b.y), cvt2bf(b.z, b.w)};
    return __builtin_bit_cast(short8, t);
}
// args pre-scaled by -L2E / +2*L2E (R9-verified helpers)
__device__ __forceinline__ float fsig2(float e) {   // sigmoid, e = -L2E*x
    return __builtin_amdgcn_rcpf(1.0f + __builtin_amdgcn_exp2f(e));
}
__device__ __forceinline__ float fth2(float e) {    // tanh, e = +2*L2E*x
    return 1.0f - 2.0f * __builtin_amdgcn_rcpf(1.0f + __builtin_amdgcn_exp2f(e));
}
__device__ __forceinline__ float ftanh(float x) {
    return 1.0f - 2.0f * __builtin_amdgcn_rcpf(1.0f + __builtin_amdgcn_exp2f(2.0f * L2E * x));
}
// barrier draining only LDS ops (NOT vmcnt -> producer global loads stay in flight)
__device__ __forceinline__ void sync_lds() {
    asm volatile("s_waitcnt lgkmcnt(0)\n\ts_barrier" ::: "memory");
}

__global__ __launch_bounds__(NTHR, 2) void lstm_persistent(
    const float* __restrict__ xin,
    const float* __restrict__ Wf, const float* __restrict__ Uf, const float* __restrict__ bfp,
    const float* __restrict__ Wi, const float* __restrict__ Ui, const float* __restrict__ bip,
    const float* __restrict__ Wc, const float* __restrict__ Uc, const float* __restrict__ bcp,
    const float* __restrict__ Wo, const float* __restrict__ Uo, const float* __restrict__ bop,
    float* __restrict__ out)
{
    __shared__ float Gx[2][16 * GXSTR];              // pre-scaled xproj, dbuf by group parity
    __shared__ __align__(8) char A1[2][2 * A1STRB];  // h fp8-e4m3, dbuf by step parity

    const int tid  = threadIdx.x;
    const int wave = tid >> 6;     // 0..7
    const int lane = tid & 63;
    const int quad = lane >> 4;    // 0..3
    const int nlo  = lane & 15;
    const int blk  = blockIdx.x;

    const float* Wg[4] = {Wf, Wi, Wc, Wo};
    const float* Ug[4] = {Uf, Ui, Uc, Uo};
    const float* Bg[4] = {bfp, bip, bcp, bop};
    const float scg[4] = {-L2E, -L2E, 2.0f * L2E, -L2E};

    if (wave < 4) {
        // ======================= CONSUMER =======================
        __builtin_amdgcn_s_setprio(1);   // chain wave is latency-critical
        const int ti_s = quad & 1;
        const int prow = quad >> 1;
        const int u_s  = 32 * wave + 16 * ti_s + nlo;

        // recurrent U as fp8 B-fragments: byte j of dword d -> k = quad*32+4d+j
        intx8 bU8[4][2];
#pragma unroll
        for (int g = 0; g < 4; ++g)
#pragma unroll
            for (int ti = 0; ti < 2; ++ti) {
                const int uc = 32 * wave + 16 * ti + nlo;
#pragma unroll
                for (int d = 0; d < 8; ++d) {
                    const int k0 = quad * 32 + d * 4;
                    int pk = __builtin_amdgcn_cvt_pk_fp8_f32(
                        Ug[g][(k0 + 0) * U_SZ + uc], Ug[g][(k0 + 1) * U_SZ + uc], 0, 0);
                    pk = __builtin_amdgcn_cvt_pk_fp8_f32(
                        Ug[g][(k0 + 2) * U_SZ + uc], Ug[g][(k0 + 3) * U_SZ + uc], pk, 1);
                    bU8[g][ti][d] = pk;
                }
            }
        float c_st = 0.0f;

        // zero both h buffers (h(0)=0); consumer tids are 0..255
        for (int i = tid; i < 2 * 2 * A1STRB; i += 256) ((char*)A1)[i] = 0;
        __syncthreads();

        for (int g = 0; g < 128; ++g) {
            const float* GxR = &Gx[g & 1][0];
#pragma unroll
            for (int j = 0; j < 8; ++j) {
                // ---- reads first: h fragment (2x b128) then xproj (b128) ----
                const char* ap = &A1[j & 1][(nlo >> 3) * A1STRB + quad * 32];
                intx4 alo = *(const intx4*)(ap);
                intx4 ahi = *(const intx4*)(ap + 16);
                floatx4 gx = *(const floatx4*)&GxR[(2 * j + prow) * GXSTR + 4 * u_s];
                intx8 a8 = {alo.x, alo.y, alo.z, alo.w, ahi.x, ahi.y, ahi.z, ahi.w};
                const floatx4 z = (floatx4){0.f, 0.f, 0.f, 0.f};

                // ---- 8 scaled fp8 MFMAs back-to-back (R8 order) ----
                floatx4 acc0[4], acc1[4];
#pragma unroll
                for (int gt = 0; gt < 4; ++gt)
                    acc0[gt] = __builtin_amdgcn_mfma_scale_f32_16x16x128_f8f6f4(
                        a8, bU8[gt][0], z, 0, 0, 0, 0x7f7f7f7f, 0, 0x7f7f7f7f);
#pragma unroll
                for (int gt = 0; gt < 4; ++gt)
                    acc1[gt] = __builtin_amdgcn_mfma_scale_f32_16x16x128_f8f6f4(
                        a8, bU8[gt][1], z, 0, 0, 0, 0x7f7f7f7f, 0, 0x7f7f7f7f);

                // ---- select-before-trans + log2e-folded activations ----
                float fg = fsig2(__builtin_fmaf(ti_s ? acc1[0][0] : acc0[0][0], -L2E, gx[0]));
                float ig = fsig2(__builtin_fmaf(ti_s ? acc1[1][0] : acc0[1][0], -L2E, gx[1]));
                float ct = fth2(__builtin_fmaf(ti_s ? acc1[2][0] : acc0[2][0], 2.0f * L2E, gx[2]));
                float og = fsig2(__builtin_fmaf(ti_s ? acc1[3][0] : acc0[3][0], -L2E, gx[3]));

                float c = fg * c_st + ig * ct;
                float h = og * ftanh(c);
                c_st = c;

                if (g == 127 && j == 7) {
                    if (prow == 0) out[(size_t)blk * U_SZ + u_s] = h;
                } else {
                    int pk = __builtin_amdgcn_cvt_pk_fp8_f32(h, h, 0, 0);
                    A1[(j & 1) ^ 1][prow * A1STRB + u_s] = (char)(pk & 0xff);
                }
                sync_lds();
            }
        }
    } else {
        // ======================= PRODUCER =======================
        // wave p owns u-tiles {2p, 2p+1} x 4 gates = 8 N-tiles; 1 tile/step.
        const int p = wave - 4;
        const int t_off = nlo >> 1;    // A-frag row m=nlo -> (t_off, brow dup'd)

        // bW fragments for 8 tiles (tau: gt=tau>>1, ut=2p+(tau&1)), K=64 (2 kt)
        // + per-tile bias (added then scaled by scg at the Gx write).
        short8 bWp[8][2];
        float  bw[8];
#pragma unroll
        for (int tau = 0; tau < 8; ++tau) {
            const int gt = tau >> 1;
            const int uc = 16 * (2 * p + (tau & 1)) + nlo;
            bw[tau] = Bg[gt][uc];
#pragma unroll
            for (int kt = 0; kt < 2; ++kt)
#pragma unroll
                for (int jj = 0; jj < 8; ++jj) {
                    int k = kt * 32 + quad * 8 + jj;
                    bWp[tau][kt][jj] = f2bf(Wg[gt][k * U_SZ + uc]);
                }
        }

        // ROWS=1: both brow halves read the same batch row (duplication).
        const float* xg = xin + ((size_t)blk * T_SZ) * D_SZ + quad * 8;

        // ---- prologue: xproj(0) -> Gx[0]; xa = x(1); xq = x(2) in flight ----
        float4 p0 = *(const float4*)(xg + (size_t)t_off * D_SZ + 0);
        float4 p1 = *(const float4*)(xg + (size_t)t_off * D_SZ + 4);
        float4 p2 = *(const float4*)(xg + (size_t)t_off * D_SZ + 32);
        float4 p3 = *(const float4*)(xg + (size_t)t_off * D_SZ + 36);
        float4 q0 = *(const float4*)(xg + (size_t)(8 + t_off) * D_SZ + 0);
        float4 q1 = *(const float4*)(xg + (size_t)(8 + t_off) * D_SZ + 4);
        float4 q2 = *(const float4*)(xg + (size_t)(8 + t_off) * D_SZ + 32);
        float4 q3 = *(const float4*)(xg + (size_t)(8 + t_off) * D_SZ + 36);

        short8 xa0 = pk8(p0, p1);
        short8 xa1 = pk8(p2, p3);
#pragma unroll
        for (int tau = 0; tau < 8; ++tau) {
            const int gt = tau >> 1;
            const int uc = 16 * (2 * p + (tau & 1)) + nlo;
            floatx4 acc = (floatx4){0.f, 0.f, 0.f, 0.f};
            acc = __builtin_amdgcn_mfma_f32_16x16x32_bf16(xa0, bWp[tau][0], acc, 0, 0, 0);
            acc = __builtin_amdgcn_mfma_f32_16x16x32_bf16(xa1, bWp[tau][1], acc, 0, 0, 0);
#pragma unroll
            for (int r = 0; r < 4; ++r)
                Gx[0][(quad * 4 + r) * GXSTR + 4 * uc + gt] = (acc[r] + bw[tau]) * scg[gt];
        }
        // xa = x(1)
        xa0 = pk8(q0, q1);
        xa1 = pk8(q2, q3);
        // xq = x(2), in flight
        float4 xq0 = *(const float4*)(xg + (size_t)(16 + t_off) * D_SZ + 0);
        float4 xq1 = *(const float4*)(xg + (size_t)(16 + t_off) * D_SZ + 4);
        float4 xq2 = *(const float4*)(xg + (size_t)(16 + t_off) * D_SZ + 32);
        float4 xq3 = *(const float4*)(xg + (size_t)(16 + t_off) * D_SZ + 36);
        __syncthreads();

        short8 xn0 = xa0, xn1 = xa1;
        for (int g = 0; g < 128; ++g) {
            float* GxW = &Gx[(g + 1) & 1][0];
#pragma unroll
            for (int j = 0; j < 8; ++j) {
                if (j == 0 && g <= 125) {   // cvt xq -> x(g+2) frags
                    xn0 = pk8(xq0, xq1);
                    xn1 = pk8(xq2, xq3);
                }
                if (j == 2 && g <= 124) {   // issue loads of x(g+3)
                    const float* b = xg + (size_t)(8 * (g + 3) + t_off) * D_SZ;
                    xq0 = *(const float4*)(b + 0);
                    xq1 = *(const float4*)(b + 4);
                    xq2 = *(const float4*)(b + 32);
                    xq3 = *(const float4*)(b + 36);
                }
                if (g < 127) {              // tile tau=j of xproj(g+1)
                    const int gt = j >> 1;
                    const int uc = 16 * (2 * p + (j & 1)) + nlo;
                    floatx4 acc = (floatx4){0.f, 0.f, 0.f, 0.f};
                    acc = __builtin_amdgcn_mfma_f32_16x16x32_bf16(xa0, bWp[j][0], acc, 0, 0, 0);
                    acc = __builtin_amdgcn_mfma_f32_16x16x32_bf16(xa1, bWp[j][1], acc, 0, 0, 0);
#pragma unroll
                    for (int r = 0; r < 4; ++r)
                        GxW[(quad * 4 + r) * GXSTR + 4 * uc + gt] = (acc[r] + bw[j]) * scg[gt];
                }
                sync_lds();
            }
            xa0 = xn0; xa1 = xn1;
        }
    }
}

extern "C" void kernel_launch(void* const* d_in, const int* in_sizes, int n_in,
                              void* d_out, int out_size, void* d_ws, size_t ws_size,
                              hipStream_t stream) {
    (void)in_sizes; (void)n_in; (void)d_ws; (void)ws_size; (void)out_size;
    const float* xin = (const float*)d_in[0];
    const float* Wf  = (const float*)d_in[1];
    const float* Uf  = (const float*)d_in[2];
    const float* bf  = (const float*)d_in[3];
    const float* Wi  = (const float*)d_in[4];
    const float* Ui  = (const float*)d_in[5];
    const float* bi  = (const float*)d_in[6];
    const float* Wc  = (const float*)d_in[7];
    const float* Uc  = (const float*)d_in[8];
    const float* bc  = (const float*)d_in[9];
    const float* Wo  = (const float*)d_in[10];
    const float* Uo  = (const float*)d_in[11];
    const float* bo  = (const float*)d_in[12];
    float* out = (float*)d_out;

    hipLaunchKernelGGL(lstm_persistent, dim3(NBLK), dim3(NTHR), 0, stream,
                       xin, Wf, Uf, bf, Wi, Ui, bi, Wc, Uc, bc, Wo, Uo, bo, out);
}

// Round 6
// 509.579 us; speedup vs baseline: 1.8833x; 1.8833x over previous
//
#include <hip/hip_runtime.h>
#include <stdint.h>

// ManualLSTM: B=512, T=1024, D=64, U=128.
// R13: one 16-wave workgroup per CU (guaranteed residency), thin consumers.
// Diagnosis of R7-R12: occupancy pinned at 8 waves/CU every round ->
// true per-wave regs (arch VGPR 128 + AGPR accs, unified file) land in the
// 129-256 band -> 2 waves/SIMD cap -> multi-block co-residency impossible.
// Fix: NTHR=1024 (16 waves, single WG is never split; launch_bounds forces
// <=128 unified regs) and use the extra waves to THIN the chain critical path:
//  - waves 0-7 = consumers, each owns 16 u-cols: only 4 scaled fp8 MFMAs/step
//    (was 8), no ti-select, bU8 halves to 32 regs.
//  - waves 8-15 = producers (separate waves -- R9's merge regressed), each
//    owns 1 u-subtile x 4 gates = 4 xproj tiles/group (1 tile per odd step).
// ROWS=2 kept: same math/tiles as R8, one chain per block, 256 blocks.
// Consumer order = burst-then-activate (R11's interleave regressed).
// Math = R9-verified log2e fold (producer stores scg*(xW+b)).
// Gx race-free: consumers read Gx[g&1], producers write Gx[(g+1)&1].
// A1 (h fp8) step-parity dbuf; sync_lds drains lgkm only (x loads in flight).

typedef __attribute__((ext_vector_type(8))) short short8;
typedef __attribute__((ext_vector_type(4))) float floatx4;
typedef __attribute__((ext_vector_type(4))) int   intx4;
typedef __attribute__((ext_vector_type(8))) int   intx8;

#define B_SZ   512
#define T_SZ   1024
#define D_SZ   64
#define U_SZ   128
#define ROWS   2
#define NBLK   (B_SZ / ROWS)   // 256 blocks, 1 per CU
#define NTHR   1024            // 16 waves: 0-7 consumers, 8-15 producers
#define A1STRB 160             // h row stride in BYTES (128 fp8 + 32 pad)
#define GXSTR  524             // Gx row stride in fp32
#define L2E    1.4426950408889634f

__device__ __forceinline__ short f2bf(float f) {
    uint32_t u = __builtin_bit_cast(uint32_t, f);
    uint32_t r = (u + 0x7fffu + ((u >> 16) & 1u)) >> 16;   // RNE
    return (short)r;
}
__device__ __forceinline__ int cvt2bf(float lo, float hi) {
    int r;
    asm("v_cvt_pk_bf16_f32 %0, %1, %2" : "=v"(r) : "v"(lo), "v"(hi));
    return r;
}
__device__ __forceinline__ short8 pk8(float4 a, float4 b) {
    intx4 t = {cvt2bf(a.x, a.y), cvt2bf(a.z, a.w), cvt2bf(b.x, b.y), cvt2bf(b.z, b.w)};
    return __builtin_bit_cast(short8, t);
}
// args pre-scaled by -L2E / +2*L2E (R9-verified helpers)
__device__ __forceinline__ float fsig2(float e) {   // sigmoid, e = -L2E*x
    return __builtin_amdgcn_rcpf(1.0f + __builtin_amdgcn_exp2f(e));
}
__device__ __forceinline__ float fth2(float e) {    // tanh, e = +2*L2E*x
    return 1.0f - 2.0f * __builtin_amdgcn_rcpf(1.0f + __builtin_amdgcn_exp2f(e));
}
__device__ __forceinline__ float ftanh(float x) {
    return 1.0f - 2.0f * __builtin_amdgcn_rcpf(1.0f + __builtin_amdgcn_exp2f(2.0f * L2E * x));
}
// barrier draining only LDS ops (NOT vmcnt -> producer global loads stay in flight)
__device__ __forceinline__ void sync_lds() {
    asm volatile("s_waitcnt lgkmcnt(0)\n\ts_barrier" ::: "memory");
}

__global__ __launch_bounds__(NTHR, 4) void lstm_persistent(
    const float* __restrict__ xin,
    const float* __restrict__ Wf, const float* __restrict__ Uf, const float* __restrict__ bfp,
    const float* __restrict__ Wi, const float* __restrict__ Ui, const float* __restrict__ bip,
    const float* __restrict__ Wc, const float* __restrict__ Uc, const float* __restrict__ bcp,
    const float* __restrict__ Wo, const float* __restrict__ Uo, const float* __restrict__ bop,
    float* __restrict__ out)
{
    __shared__ float Gx[2][16 * GXSTR];              // pre-scaled xproj, dbuf by group parity
    __shared__ __align__(8) char A1[2][2 * A1STRB];  // h fp8-e4m3, dbuf by step parity

    const int tid  = threadIdx.x;
    const int wave = tid >> 6;     // 0..15
    const int lane = tid & 63;
    const int quad = lane >> 4;    // 0..3
    const int nlo  = lane & 15;
    const int blk  = blockIdx.x;

    const float* Wg[4] = {Wf, Wi, Wc, Wo};
    const float* Ug[4] = {Uf, Ui, Uc, Uo};
    const float* Bg[4] = {bfp, bip, bcp, bop};
    const float scg[4] = {-L2E, -L2E, 2.0f * L2E, -L2E};

    if (wave < 8) {
        // ======================= CONSUMER (8 thin waves) =======================
        __builtin_amdgcn_s_setprio(1);   // chain waves are latency-critical
        const int  prow = quad >> 1;        // C rows quad*4+r -> batch row quad>>1
        const bool wr   = (quad & 1) == 0;  // quads 1,3 mirror 0,2
        const int  u_s  = 16 * wave + nlo;  // this wave's u-column

        // recurrent U as fp8 B-fragments (16 cols, 4 gates): byte j of dword d
        // -> k = quad*32 + 4d + j; col = nlo within the wave's 16-col tile.
        intx8 bU8[4];
#pragma unroll
        for (int gt = 0; gt < 4; ++gt)
#pragma unroll
            for (int d = 0; d < 8; ++d) {
                const int k0 = quad * 32 + d * 4;
                int pk = __builtin_amdgcn_cvt_pk_fp8_f32(
                    Ug[gt][(k0 + 0) * U_SZ + u_s], Ug[gt][(k0 + 1) * U_SZ + u_s], 0, 0);
                pk = __builtin_amdgcn_cvt_pk_fp8_f32(
                    Ug[gt][(k0 + 2) * U_SZ + u_s], Ug[gt][(k0 + 3) * U_SZ + u_s], pk, 1);
                bU8[gt][d] = pk;
            }
        float c_st = 0.0f;

        // zero both h buffers (h(0)=0); consumer tids are 0..511
        for (int i = tid; i < 2 * 2 * A1STRB; i += 512) ((char*)A1)[i] = 0;
        __syncthreads();

        for (int g = 0; g < 128; ++g) {
            const float* GxR = &Gx[g & 1][0];
#pragma unroll
            for (int j = 0; j < 8; ++j) {
                // ---- reads first: h fragment (2x b128) then xproj (b128) ----
                const char* ap = &A1[j & 1][(nlo >> 3) * A1STRB + quad * 32];
                intx4 alo = *(const intx4*)(ap);
                intx4 ahi = *(const intx4*)(ap + 16);
                floatx4 gx = *(const floatx4*)&GxR[(2 * j + prow) * GXSTR + 4 * u_s];
                intx8 a8 = {alo.x, alo.y, alo.z, alo.w, ahi.x, ahi.y, ahi.z, ahi.w};
                const floatx4 z = (floatx4){0.f, 0.f, 0.f, 0.f};

                // ---- 4 scaled fp8 MFMAs back-to-back (burst-then-activate) ----
                floatx4 acc[4];
#pragma unroll
                for (int gt = 0; gt < 4; ++gt)
                    acc[gt] = __builtin_amdgcn_mfma_scale_f32_16x16x128_f8f6f4(
                        a8, bU8[gt], z, 0, 0, 0, 0x7f7f7f7f, 0, 0x7f7f7f7f);

                // ---- log2e-folded activations (no ti-select needed) ----
                float fg = fsig2(__builtin_fmaf(acc[0][0], -L2E, gx[0]));
                float ig = fsig2(__builtin_fmaf(acc[1][0], -L2E, gx[1]));
                float ct = fth2(__builtin_fmaf(acc[2][0], 2.0f * L2E, gx[2]));
                float og = fsig2(__builtin_fmaf(acc[3][0], -L2E, gx[3]));

                float c = fg * c_st + ig * ct;
                float h = og * ftanh(c);
                c_st = c;

                if (g == 127 && j == 7) {
                    if (wr) out[(size_t)(blk * ROWS + prow) * U_SZ + u_s] = h;
                } else if (wr) {
                    int pk = __builtin_amdgcn_cvt_pk_fp8_f32(h, h, 0, 0);
                    A1[(j & 1) ^ 1][prow * A1STRB + u_s] = (char)(pk & 0xff);
                }
                sync_lds();
            }
        }
    } else {
        // ======================= PRODUCER (8 waves) =======================
        // wave p owns u-subtile p x 4 gates = 4 N-tiles; 1 tile per odd step.
        const int p = wave - 8;
        const int brow  = nlo & 1;     // A-frag row m=nlo -> (t_off, brow)
        const int t_off = nlo >> 1;
        const int uc    = 16 * p + nlo;

        // bW fragments for 4 tiles (one per gate), K=64 (2 kt) + bias.
        short8 bWp[4][2];
        float  bw[4];
#pragma unroll
        for (int gt = 0; gt < 4; ++gt) {
            bw[gt] = Bg[gt][uc];
#pragma unroll
            for (int kt = 0; kt < 2; ++kt)
#pragma unroll
                for (int jj = 0; jj < 8; ++jj) {
                    int k = kt * 32 + quad * 8 + jj;
                    bWp[gt][kt][jj] = f2bf(Wg[gt][k * U_SZ + uc]);
                }
        }

        const float* xg = xin + ((size_t)(blk * ROWS + brow) * T_SZ) * D_SZ + quad * 8;

        // ---- prologue: xproj(0) -> Gx[0]; xa = x(1); xq = x(2) in flight ----
        float4 p0 = *(const float4*)(xg + (size_t)t_off * D_SZ + 0);
        float4 p1 = *(const float4*)(xg + (size_t)t_off * D_SZ + 4);
        float4 p2 = *(const float4*)(xg + (size_t)t_off * D_SZ + 32);
        float4 p3 = *(const float4*)(xg + (size_t)t_off * D_SZ + 36);
        float4 q0 = *(const float4*)(xg + (size_t)(8 + t_off) * D_SZ + 0);
        float4 q1 = *(const float4*)(xg + (size_t)(8 + t_off) * D_SZ + 4);
        float4 q2 = *(const float4*)(xg + (size_t)(8 + t_off) * D_SZ + 32);
        float4 q3 = *(const float4*)(xg + (size_t)(8 + t_off) * D_SZ + 36);

        short8 xa0 = pk8(p0, p1);
        short8 xa1 = pk8(p2, p3);
#pragma unroll
        for (int gt = 0; gt < 4; ++gt) {
            floatx4 acc = (floatx4){0.f, 0.f, 0.f, 0.f};
            acc = __builtin_amdgcn_mfma_f32_16x16x32_bf16(xa0, bWp[gt][0], acc, 0, 0, 0);
            acc = __builtin_amdgcn_mfma_f32_16x16x32_bf16(xa1, bWp[gt][1], acc, 0, 0, 0);
#pragma unroll
            for (int r = 0; r < 4; ++r)
                Gx[0][(quad * 4 + r) * GXSTR + 4 * uc + gt] = (acc[r] + bw[gt]) * scg[gt];
        }
        // xa = x(1)
        xa0 = pk8(q0, q1);
        xa1 = pk8(q2, q3);
        // xq = x(2), in flight
        float4 xq0 = *(const float4*)(xg + (size_t)(16 + t_off) * D_SZ + 0);
        float4 xq1 = *(const float4*)(xg + (size_t)(16 + t_off) * D_SZ + 4);
        float4 xq2 = *(const float4*)(xg + (size_t)(16 + t_off) * D_SZ + 32);
        float4 xq3 = *(const float4*)(xg + (size_t)(16 + t_off) * D_SZ + 36);
        __syncthreads();

        short8 xn0 = xa0, xn1 = xa1;
        for (int g = 0; g < 128; ++g) {
            float* GxW = &Gx[(g + 1) & 1][0];
#pragma unroll
            for (int j = 0; j < 8; ++j) {
                if (j == 0 && g <= 125) {   // cvt xq -> x(g+2) frags
                    xn0 = pk8(xq0, xq1);
                    xn1 = pk8(xq2, xq3);
                }
                if (j == 2 && g <= 124) {   // issue loads of x(g+3)
                    const float* b = xg + (size_t)(8 * (g + 3) + t_off) * D_SZ;
                    xq0 = *(const float4*)(b + 0);
                    xq1 = *(const float4*)(b + 4);
                    xq2 = *(const float4*)(b + 32);
                    xq3 = *(const float4*)(b + 36);
                }
                if ((j & 1) && g < 127) {   // gate gt=j>>1 tile of xproj(g+1)
                    const int gt = j >> 1;
                    floatx4 acc = (floatx4){0.f, 0.f, 0.f, 0.f};
                    acc = __builtin_amdgcn_mfma_f32_16x16x32_bf16(xa0, bWp[gt][0], acc, 0, 0, 0);
                    acc = __builtin_amdgcn_mfma_f32_16x16x32_bf16(xa1, bWp[gt][1], acc, 0, 0, 0);
#pragma unroll
                    for (int r = 0; r < 4; ++r)
                        GxW[(quad * 4 + r) * GXSTR + 4 * uc + gt] = (acc[r] + bw[gt]) * scg[gt];
                }
                sync_lds();
            }
            xa0 = xn0; xa1 = xn1;
        }
    }
}

extern "C" void kernel_launch(void* const* d_in, const int* in_sizes, int n_in,
                              void* d_out, int out_size, void* d_ws, size_t ws_size,
                              hipStream_t stream) {
    (void)in_sizes; (void)n_in; (void)d_ws; (void)ws_size; (void)out_size;
    const float* xin = (const float*)d_in[0];
    const float* Wf  = (const float*)d_in[1];
    const float* Uf  = (const float*)d_in[2];
    const float* bf  = (const float*)d_in[3];
    const float* Wi  = (const float*)d_in[4];
    const float* Ui  = (const float*)d_in[5];
    const float* bi  = (const float*)d_in[6];
    const float* Wc  = (const float*)d_in[7];
    const float* Uc  = (const float*)d_in[8];
    const float* bc  = (const float*)d_in[9];
    const float* Wo  = (const float*)d_in[10];
    const float* Uo  = (const float*)d_in[11];
    const float* bo  = (const float*)d_in[12];
    float* out = (float*)d_out;

    hipLaunchKernelGGL(lstm_persistent, dim3(NBLK), dim3(NTHR), 0, stream,
                       xin, Wf, Uf, bf, Wi, Ui, bi, Wc, Uc, bc, Wo, Uo, bo, out);
}